// Round 7
// baseline (280.352 us; speedup 1.0000x reference)
//
#include <hip/hip_runtime.h>

// QuantLinearFP8: out[m,n] = sum_k x[m,k] * w[n,k] * scale[n, k/128] + bias[n]
// M=64, K=4096, N=11008, G=128.
//
// R10: KSPLIT 8 -> 4 (epilogue-atomic ablation). R6-R9 showed pass1's
// schedule is not the limiter (3 different pipelines within 5 us) -> test the
// remaining un-ablated cost: 5.6M f32 atomics on the 2.8 MB out surface.
// KSPLIT=4 halves atomics + scale fetches + per-block overhead; per-CU max
// w-bytes unchanged (768 KB -> same load balance); 688 blocks all co-resident
// at 3/CU. Pipeline = R9 verbatim: wave-private w LDS ring (5 x 8 KB),
// zero barriers, distance-4 prefetch, airtight vmcnt window (retain 20),
// x register ring from pre-converted xf frags.
// ws layout: only xf bf16 (512 KB) at offset 0.

#define Md 64
#define Kd 4096
#define Nd 11008
#define NGROUPS 32
#define BN 64
#define KSPLIT 4
#define KCHUNK (Kd / KSPLIT)     // 1024
#define NST (KCHUNK / 32)        // 32 BK=32 stages per chunk
#define NGRP (KCHUNK / 128)      // 8 scale groups per chunk
#define NBUF 5                   // w LDS ring
#define DIST 4                   // prefetch distance

typedef __attribute__((ext_vector_type(8))) __bf16 bf16x8;
typedef __attribute__((ext_vector_type(4))) float f32x4;

#define AS1 __attribute__((address_space(1)))
#define AS3 __attribute__((address_space(3)))

// blocks [0,128):   xf[kb][t][lane][j] = x[t*16+(lane&15)][kb*32+(lane>>4)*8+j]
// blocks [128,816): out[i] = bias[i % Nd]  (bias pre-init for atomic split-K)
__global__ __launch_bounds__(256)
void prep(const float* __restrict__ x, __bf16* __restrict__ xf,
          const float* __restrict__ bias, float* __restrict__ out)
{
    if (blockIdx.x < 128) {
        const int tid  = blockIdx.x * 256 + threadIdx.x;  // frag id, 32768
        const int lane = tid & 63;
        const int t    = (tid >> 6) & 3;
        const int kb   = tid >> 8;
        const int row  = t * 16 + (lane & 15);
        const int col  = kb * 32 + (lane >> 4) * 8;
        const float4 a = *(const float4*)(x + (size_t)row * Kd + col);
        const float4 b = *(const float4*)(x + (size_t)row * Kd + col + 4);
        bf16x8 v = {(__bf16)a.x, (__bf16)a.y, (__bf16)a.z, (__bf16)a.w,
                    (__bf16)b.x, (__bf16)b.y, (__bf16)b.z, (__bf16)b.w};
        *(bf16x8*)(xf + (size_t)tid * 8) = v;
    } else {
        const int i4 = (blockIdx.x - 128) * 256 + threadIdx.x; // 176128 = Md*Nd/4
        const int n  = (i4 * 4) % Nd;                          // Nd % 4 == 0
        *(float4*)(out + (size_t)i4 * 4) = *(const float4*)(bias + n);
    }
}

__global__ __launch_bounds__(256, 3)
void qlinear_pass1(const float* __restrict__ w,
                   const __bf16* __restrict__ xf,
                   const float* __restrict__ scale,
                   float* __restrict__ out)
{
    const int tid  = threadIdx.x;
    const int wv   = tid >> 6;         // wave -> n-substripe
    const int lane = tid & 63;
    const int quad = lane >> 4;
    const int ln   = lane & 15;

    const int n0 = blockIdx.x * BN;
    const int ky = blockIdx.y;
    const int k0 = ky * KCHUNK;

    __shared__ alignas(16) float lds_w[NBUF][BN * 32];   // 5 x 8 KB

    // wave-private w staging: 2 issues/stage cover rows wv*16..+15
    // (8 rows x 128 B contiguous each). Source 16B-chunk XOR-swizzled by row
    // so linear LDS holds the swizzled layout (rule 21).
    const float* src[2];
    #pragma unroll
    for (int j = 0; j < 2; ++j) {
        const int r   = wv * 16 + j * 8 + (lane >> 3);   // row this lane feeds
        const int c16 = (lane & 7) ^ (r & 7);            // swizzled chunk 0..7
        src[j] = w + (size_t)(n0 + r) * Kd + k0 + c16 * 4;
    }

#define WSTAGE(S, B)                                                           \
    do {                                                                       \
        _Pragma("unroll")                                                      \
        for (int j = 0; j < 2; ++j)                                           \
            __builtin_amdgcn_global_load_lds(                                  \
                (const AS1 void*)(src[j] + (S) * 32),                          \
                (AS3 void*)&lds_w[B][(wv * 16 + j * 8) * 32], 16, 0, 0);       \
    } while (0)

    // x register ring: 4 frags per stage, prefetched at distance 4
    const __bf16* xp = xf + (size_t)ky * NST * 4 * 512 + (size_t)lane * 8;
    bf16x8 xr[4][4];

#define XLOAD(SLOT, S)                                                         \
    do {                                                                       \
        _Pragma("unroll")                                                      \
        for (int t = 0; t < 4; ++t)                                           \
            xr[SLOT][t] = *(const bf16x8*)(xp + ((size_t)(S) * 4 + t) * 512);  \
    } while (0)

    // scales: load and fully drain BEFORE the counted window starts
    const int nrow = n0 + wv * 16 + ln;
    float4 sc4a = *(const float4*)(scale + (size_t)nrow * NGROUPS + ky * NGRP);
    float4 sc4b = *(const float4*)(scale + (size_t)nrow * NGROUPS + ky * NGRP + 4);
    asm volatile("s_waitcnt vmcnt(0)" ::: "memory");
    const float sc[8] = {sc4a.x, sc4a.y, sc4a.z, sc4a.w,
                         sc4b.x, sc4b.y, sc4b.z, sc4b.w};

    // frag-read row + swizzle key
    const int rr = wv * 16 + ln;
    const int rx = rr & 7;

    f32x4 acc[4], pg[4];
    #pragma unroll
    for (int t = 0; t < 4; ++t) {
        acc[t] = (f32x4){0.f, 0.f, 0.f, 0.f};
        pg[t]  = (f32x4){0.f, 0.f, 0.f, 0.f};
    }

    // prologue: stages 0..3 in flight, interleaved W,X (6 ops per stage)
    WSTAGE(0, 0); XLOAD(0, 0);
    WSTAGE(1, 1); XLOAD(1, 1);
    WSTAGE(2, 2); XLOAD(2, 2);
    WSTAGE(3, 3); XLOAD(3, 3);

    #pragma unroll
    for (int s = 0; s < NST; ++s) {
        // issue next w stage (top of window)
        if (s + DIST < NST) WSTAGE(s + DIST, (s + DIST) % NBUF);

        // single counted wait: drains exactly stage s (w pair + x quad),
        // retains stages s+1..s+4 (26 in flight - stage s's 6 = 20).
        if (s + DIST < NST)      asm volatile("s_waitcnt vmcnt(20)" ::: "memory");
        else if (s == NST - 4)   asm volatile("s_waitcnt vmcnt(18)" ::: "memory");
        else if (s == NST - 3)   asm volatile("s_waitcnt vmcnt(12)" ::: "memory");
        else if (s == NST - 2)   asm volatile("s_waitcnt vmcnt(6)"  ::: "memory");
        else                     asm volatile("s_waitcnt vmcnt(0)"  ::: "memory");
        __builtin_amdgcn_sched_barrier(0);

        // w frag: two swizzled 16B chunks of (wave-private) row rr
        const int buf = s % NBUF;
        const int cA  = (quad * 2) ^ rx;
        const int cB  = (quad * 2 + 1) ^ rx;
        f32x4 fa = *(const f32x4*)&lds_w[buf][rr * 32 + cA * 4];
        f32x4 fb = *(const f32x4*)&lds_w[buf][rr * 32 + cB * 4];
        bf16x8 wf = {(__bf16)fa.x, (__bf16)fa.y, (__bf16)fa.z, (__bf16)fa.w,
                     (__bf16)fb.x, (__bf16)fb.y, (__bf16)fb.z, (__bf16)fb.w};

        #pragma unroll
        for (int t = 0; t < 4; ++t)
            pg[t] = __builtin_amdgcn_mfma_f32_16x16x32_bf16(xr[s & 3][t], wf,
                                                            pg[t], 0, 0, 0);

        // refill the x ring slot just consumed (bottom of window)
        if (s + DIST < NST) XLOAD(s & 3, s + DIST);

        // per-128k scale group boundary: fold pg into acc
        if ((s & 3) == 3) {
            const float sg = sc[s >> 2];
            #pragma unroll
            for (int t = 0; t < 4; ++t) {
                #pragma unroll
                for (int r = 0; r < 4; ++r) {
                    acc[t][r] += sg * pg[t][r];
                    pg[t][r] = 0.f;
                }
            }
        }
    }

    // atomic split-K epilogue -> out[m][n]  (C/D: m = t*16+quad*4+r, col = ln)
    float* op = out + n0 + wv * 16 + ln;
    #pragma unroll
    for (int t = 0; t < 4; ++t)
        #pragma unroll
        for (int r = 0; r < 4; ++r)
            unsafeAtomicAdd(&op[(size_t)(t * 16 + quad * 4 + r) * Nd], acc[t][r]);
#undef WSTAGE
#undef XLOAD
}

extern "C" void kernel_launch(void* const* d_in, const int* in_sizes, int n_in,
                              void* d_out, int out_size, void* d_ws, size_t ws_size,
                              hipStream_t stream) {
    const float* x     = (const float*)d_in[0];  // [64][4096]
    const float* w     = (const float*)d_in[1];  // [11008][4096]
    const float* scale = (const float*)d_in[2];  // [11008][32]
    const float* bias  = (const float*)d_in[3];  // [11008]
    float* out = (float*)d_out;                  // [64][11008] f32
    float* ws  = (float*)d_ws;                   // xf bf16 (512 KB)

    __bf16* xf = (__bf16*)ws;                    // 16B-aligned

    prep<<<816, 256, 0, stream>>>(x, xf, bias, out);

    dim3 grid1(Nd / BN, KSPLIT);
    qlinear_pass1<<<grid1, 256, 0, stream>>>(w, xf, scale, out);
}

// Round 8
// 266.878 us; speedup vs baseline: 1.0505x; 1.0505x over previous
//
#include <hip/hip_runtime.h>

// QuantLinearFP8: out[m,n] = sum_k x[m,k] * w[n,k] * scale[n, k/128] + bias[n]
// M=64, K=4096, N=11008, G=128.
//
// R11: REVERT to R9 (best measured, 268.0 us). R10's KSPLIT=4 regressed
// +12.4 us: 688 blocks at 3/CU residency = whole grid co-resident with no
// backfill queue -> baked-in 33% CU tail imbalance (176 CUs x 3 blocks vs
// 80 x 2), plus 2x unrolled body. KSPLIT=8's 1376 blocks backfill
// dynamically. Atomic-count halving bought nothing -> epilogue not a cost.
//
// R9 structure: barrier-free deep pipeline.
//  (1) w LDS tile is WAVE-PRIVATE (wave wv stages rows [wv*16,wv*16+16) and
//      reads only those) -> no __syncthreads anywhere; per-wave vmcnt orders
//      LDS-DMA vs ds_read.
//  (2) x in a REGISTER ring prefetched at the same distance-4 as w so one
//      in-order vmcnt counter expresses the whole pipeline.
// Per stage s: issue W(s+4) -> s_waitcnt vmcnt(20) (retain stages s+1..s+4;
// drain exactly stage s) -> ds_read + 4 MFMA -> issue X(s+4) into the slot
// just freed. Never vmcnt(0) in steady state. w: 5-buffer LDS ring (40 KB),
// XOR-swizzled source chunks + same XOR on ds_read (rule 21).
// Scales loaded + drained before the counted window (R8 lesson).
// prep (xf convert + bias pre-init) + atomic epilogue as R6.
// ws layout: only xf bf16 (512 KB) at offset 0.

#define Md 64
#define Kd 4096
#define Nd 11008
#define NGROUPS 32
#define BN 64
#define KSPLIT 8
#define KCHUNK (Kd / KSPLIT)     // 512
#define NST (KCHUNK / 32)        // 16 BK=32 stages per chunk
#define NBUF 5                   // w LDS ring
#define DIST 4                   // prefetch distance

typedef __attribute__((ext_vector_type(8))) __bf16 bf16x8;
typedef __attribute__((ext_vector_type(4))) float f32x4;

#define AS1 __attribute__((address_space(1)))
#define AS3 __attribute__((address_space(3)))

// blocks [0,128):   xf[kb][t][lane][j] = x[t*16+(lane&15)][kb*32+(lane>>4)*8+j]
// blocks [128,816): out[i] = bias[i % Nd]  (bias pre-init for atomic split-K)
__global__ __launch_bounds__(256)
void prep(const float* __restrict__ x, __bf16* __restrict__ xf,
          const float* __restrict__ bias, float* __restrict__ out)
{
    if (blockIdx.x < 128) {
        const int tid  = blockIdx.x * 256 + threadIdx.x;  // frag id, 32768
        const int lane = tid & 63;
        const int t    = (tid >> 6) & 3;
        const int kb   = tid >> 8;
        const int row  = t * 16 + (lane & 15);
        const int col  = kb * 32 + (lane >> 4) * 8;
        const float4 a = *(const float4*)(x + (size_t)row * Kd + col);
        const float4 b = *(const float4*)(x + (size_t)row * Kd + col + 4);
        bf16x8 v = {(__bf16)a.x, (__bf16)a.y, (__bf16)a.z, (__bf16)a.w,
                    (__bf16)b.x, (__bf16)b.y, (__bf16)b.z, (__bf16)b.w};
        *(bf16x8*)(xf + (size_t)tid * 8) = v;
    } else {
        const int i4 = (blockIdx.x - 128) * 256 + threadIdx.x; // 176128 = Md*Nd/4
        const int n  = (i4 * 4) % Nd;                          // Nd % 4 == 0
        *(float4*)(out + (size_t)i4 * 4) = *(const float4*)(bias + n);
    }
}

__global__ __launch_bounds__(256, 3)
void qlinear_pass1(const float* __restrict__ w,
                   const __bf16* __restrict__ xf,
                   const float* __restrict__ scale,
                   float* __restrict__ out)
{
    const int tid  = threadIdx.x;
    const int wv   = tid >> 6;         // wave -> n-substripe
    const int lane = tid & 63;
    const int quad = lane >> 4;
    const int ln   = lane & 15;

    const int n0 = blockIdx.x * BN;
    const int ky = blockIdx.y;
    const int k0 = ky * KCHUNK;

    __shared__ alignas(16) float lds_w[NBUF][BN * 32];   // 5 x 8 KB

    // wave-private w staging: 2 issues/stage cover rows wv*16..+15
    // (8 rows x 128 B contiguous each). Source 16B-chunk XOR-swizzled by row
    // so linear LDS holds the swizzled layout (rule 21).
    const float* src[2];
    #pragma unroll
    for (int j = 0; j < 2; ++j) {
        const int r   = wv * 16 + j * 8 + (lane >> 3);   // row this lane feeds
        const int c16 = (lane & 7) ^ (r & 7);            // swizzled chunk 0..7
        src[j] = w + (size_t)(n0 + r) * Kd + k0 + c16 * 4;
    }

#define WSTAGE(S, B)                                                           \
    do {                                                                       \
        _Pragma("unroll")                                                      \
        for (int j = 0; j < 2; ++j)                                           \
            __builtin_amdgcn_global_load_lds(                                  \
                (const AS1 void*)(src[j] + (S) * 32),                          \
                (AS3 void*)&lds_w[B][(wv * 16 + j * 8) * 32], 16, 0, 0);       \
    } while (0)

    // x register ring: 4 frags per stage, prefetched at distance 4
    const __bf16* xp = xf + (size_t)ky * NST * 4 * 512 + (size_t)lane * 8;
    bf16x8 xr[4][4];

#define XLOAD(SLOT, S)                                                         \
    do {                                                                       \
        _Pragma("unroll")                                                      \
        for (int t = 0; t < 4; ++t)                                           \
            xr[SLOT][t] = *(const bf16x8*)(xp + ((size_t)(S) * 4 + t) * 512);  \
    } while (0)

    // scales: load and fully drain BEFORE the counted window starts
    const int nrow = n0 + wv * 16 + ln;
    float4 sc4 = *(const float4*)(scale + (size_t)nrow * NGROUPS + ky * 4);
    asm volatile("s_waitcnt vmcnt(0)" ::: "memory");
    const float sc[4] = {sc4.x, sc4.y, sc4.z, sc4.w};

    // frag-read row + swizzle key
    const int rr = wv * 16 + ln;
    const int rx = rr & 7;

    f32x4 acc[4], pg[4];
    #pragma unroll
    for (int t = 0; t < 4; ++t) {
        acc[t] = (f32x4){0.f, 0.f, 0.f, 0.f};
        pg[t]  = (f32x4){0.f, 0.f, 0.f, 0.f};
    }

    // prologue: stages 0..3 in flight, interleaved W,X (6 ops per stage)
    WSTAGE(0, 0); XLOAD(0, 0);
    WSTAGE(1, 1); XLOAD(1, 1);
    WSTAGE(2, 2); XLOAD(2, 2);
    WSTAGE(3, 3); XLOAD(3, 3);

    #pragma unroll
    for (int s = 0; s < NST; ++s) {
        // issue next w stage (top of window)
        if (s + DIST < NST) WSTAGE(s + DIST, (s + DIST) % NBUF);

        // single counted wait: drains exactly stage s (w pair + x quad),
        // retains stages s+1..s+4. Never 0 until the tail.
        if (s + DIST < NST)      asm volatile("s_waitcnt vmcnt(20)" ::: "memory");
        else if (s == NST - 4)   asm volatile("s_waitcnt vmcnt(18)" ::: "memory");
        else if (s == NST - 3)   asm volatile("s_waitcnt vmcnt(12)" ::: "memory");
        else if (s == NST - 2)   asm volatile("s_waitcnt vmcnt(6)"  ::: "memory");
        else                     asm volatile("s_waitcnt vmcnt(0)"  ::: "memory");
        __builtin_amdgcn_sched_barrier(0);

        // w frag: two swizzled 16B chunks of (wave-private) row rr
        const int buf = s % NBUF;
        const int cA  = (quad * 2) ^ rx;
        const int cB  = (quad * 2 + 1) ^ rx;
        f32x4 fa = *(const f32x4*)&lds_w[buf][rr * 32 + cA * 4];
        f32x4 fb = *(const f32x4*)&lds_w[buf][rr * 32 + cB * 4];
        bf16x8 wf = {(__bf16)fa.x, (__bf16)fa.y, (__bf16)fa.z, (__bf16)fa.w,
                     (__bf16)fb.x, (__bf16)fb.y, (__bf16)fb.z, (__bf16)fb.w};

        #pragma unroll
        for (int t = 0; t < 4; ++t)
            pg[t] = __builtin_amdgcn_mfma_f32_16x16x32_bf16(xr[s & 3][t], wf,
                                                            pg[t], 0, 0, 0);

        // refill the x ring slot just consumed (bottom of window)
        if (s + DIST < NST) XLOAD(s & 3, s + DIST);

        // per-128k scale group boundary: fold pg into acc
        if ((s & 3) == 3) {
            const float sg = sc[s >> 2];
            #pragma unroll
            for (int t = 0; t < 4; ++t) {
                #pragma unroll
                for (int r = 0; r < 4; ++r) {
                    acc[t][r] += sg * pg[t][r];
                    pg[t][r] = 0.f;
                }
            }
        }
    }

    // atomic split-K epilogue -> out[m][n]  (C/D: m = t*16+quad*4+r, col = ln)
    float* op = out + n0 + wv * 16 + ln;
    #pragma unroll
    for (int t = 0; t < 4; ++t)
        #pragma unroll
        for (int r = 0; r < 4; ++r)
            unsafeAtomicAdd(&op[(size_t)(t * 16 + quad * 4 + r) * Nd], acc[t][r]);
#undef WSTAGE
#undef XLOAD
}

extern "C" void kernel_launch(void* const* d_in, const int* in_sizes, int n_in,
                              void* d_out, int out_size, void* d_ws, size_t ws_size,
                              hipStream_t stream) {
    const float* x     = (const float*)d_in[0];  // [64][4096]
    const float* w     = (const float*)d_in[1];  // [11008][4096]
    const float* scale = (const float*)d_in[2];  // [11008][32]
    const float* bias  = (const float*)d_in[3];  // [11008]
    float* out = (float*)d_out;                  // [64][11008] f32
    float* ws  = (float*)d_ws;                   // xf bf16 (512 KB)

    __bf16* xf = (__bf16*)ws;                    // 16B-aligned

    prep<<<816, 256, 0, stream>>>(x, xf, bias, out);

    dim3 grid1(Nd / BN, KSPLIT);
    qlinear_pass1<<<grid1, 256, 0, stream>>>(w, xf, scale, out);
}

// Round 9
// 256.652 us; speedup vs baseline: 1.0923x; 1.0398x over previous
//
#include <hip/hip_runtime.h>

// QuantLinearFP8: out[m,n] = sum_k x[m,k] * w[n,k] * scale[n, k/128] + bias[n]
// M=64, K=4096, N=11008, G=128.
//
// R12: R11 + NON-TEMPORAL w staging (aux=2 -> CPol NT on gfx94x/gfx950).
// Theory: the harness's 688 MB ws poison fill leaves L3 100% dirty; pass1's
// 180 MB cold w stream then pays 180 MB of dirty-line writebacks concurrent
// with its fetches -> observed ~3.6-4 TB/s plateau that five different
// schedules (R5/R6/R8/R9/R11) could not move. NT (no-allocate) reads skip
// L3 allocation -> no forced evictions; the dirty poison lines are simply
// overwritten in place by the next iteration's fill (full-line writes).
// w is single-use so NT sacrifices nothing.
// Everything else is R11 verbatim (best measured, 266.9 us): wave-private
// w LDS ring (5 x 8 KB), zero barriers, distance-4 prefetch, airtight
// vmcnt window (retain 20), x register ring from pre-converted xf frags,
// atomic split-K epilogue into bias-initialized out.
// ws layout: only xf bf16 (512 KB) at offset 0.

#define Md 64
#define Kd 4096
#define Nd 11008
#define NGROUPS 32
#define BN 64
#define KSPLIT 8
#define KCHUNK (Kd / KSPLIT)     // 512
#define NST (KCHUNK / 32)        // 16 BK=32 stages per chunk
#define NBUF 5                   // w LDS ring
#define DIST 4                   // prefetch distance

typedef __attribute__((ext_vector_type(8))) __bf16 bf16x8;
typedef __attribute__((ext_vector_type(4))) float f32x4;

#define AS1 __attribute__((address_space(1)))
#define AS3 __attribute__((address_space(3)))

// blocks [0,128):   xf[kb][t][lane][j] = x[t*16+(lane&15)][kb*32+(lane>>4)*8+j]
// blocks [128,816): out[i] = bias[i % Nd]  (bias pre-init for atomic split-K)
__global__ __launch_bounds__(256)
void prep(const float* __restrict__ x, __bf16* __restrict__ xf,
          const float* __restrict__ bias, float* __restrict__ out)
{
    if (blockIdx.x < 128) {
        const int tid  = blockIdx.x * 256 + threadIdx.x;  // frag id, 32768
        const int lane = tid & 63;
        const int t    = (tid >> 6) & 3;
        const int kb   = tid >> 8;
        const int row  = t * 16 + (lane & 15);
        const int col  = kb * 32 + (lane >> 4) * 8;
        const float4 a = *(const float4*)(x + (size_t)row * Kd + col);
        const float4 b = *(const float4*)(x + (size_t)row * Kd + col + 4);
        bf16x8 v = {(__bf16)a.x, (__bf16)a.y, (__bf16)a.z, (__bf16)a.w,
                    (__bf16)b.x, (__bf16)b.y, (__bf16)b.z, (__bf16)b.w};
        *(bf16x8*)(xf + (size_t)tid * 8) = v;
    } else {
        const int i4 = (blockIdx.x - 128) * 256 + threadIdx.x; // 176128 = Md*Nd/4
        const int n  = (i4 * 4) % Nd;                          // Nd % 4 == 0
        *(float4*)(out + (size_t)i4 * 4) = *(const float4*)(bias + n);
    }
}

__global__ __launch_bounds__(256, 3)
void qlinear_pass1(const float* __restrict__ w,
                   const __bf16* __restrict__ xf,
                   const float* __restrict__ scale,
                   float* __restrict__ out)
{
    const int tid  = threadIdx.x;
    const int wv   = tid >> 6;         // wave -> n-substripe
    const int lane = tid & 63;
    const int quad = lane >> 4;
    const int ln   = lane & 15;

    const int n0 = blockIdx.x * BN;
    const int ky = blockIdx.y;
    const int k0 = ky * KCHUNK;

    __shared__ alignas(16) float lds_w[NBUF][BN * 32];   // 5 x 8 KB

    // wave-private w staging: 2 issues/stage cover rows wv*16..+15
    // (8 rows x 128 B contiguous each). Source 16B-chunk XOR-swizzled by row
    // so linear LDS holds the swizzled layout (rule 21).
    const float* src[2];
    #pragma unroll
    for (int j = 0; j < 2; ++j) {
        const int r   = wv * 16 + j * 8 + (lane >> 3);   // row this lane feeds
        const int c16 = (lane & 7) ^ (r & 7);            // swizzled chunk 0..7
        src[j] = w + (size_t)(n0 + r) * Kd + k0 + c16 * 4;
    }

// aux=2 -> CPol NT (non-temporal, no-allocate): w is single-use; avoid
// evicting the fill's dirty L3 lines (writeback storm) on our read stream.
#define WSTAGE(S, B)                                                           \
    do {                                                                       \
        _Pragma("unroll")                                                      \
        for (int j = 0; j < 2; ++j)                                           \
            __builtin_amdgcn_global_load_lds(                                  \
                (const AS1 void*)(src[j] + (S) * 32),                          \
                (AS3 void*)&lds_w[B][(wv * 16 + j * 8) * 32], 16, 0, 2);       \
    } while (0)

    // x register ring: 4 frags per stage, prefetched at distance 4
    const __bf16* xp = xf + (size_t)ky * NST * 4 * 512 + (size_t)lane * 8;
    bf16x8 xr[4][4];

#define XLOAD(SLOT, S)                                                         \
    do {                                                                       \
        _Pragma("unroll")                                                      \
        for (int t = 0; t < 4; ++t)                                           \
            xr[SLOT][t] = *(const bf16x8*)(xp + ((size_t)(S) * 4 + t) * 512);  \
    } while (0)

    // scales: load and fully drain BEFORE the counted window starts
    const int nrow = n0 + wv * 16 + ln;
    float4 sc4 = *(const float4*)(scale + (size_t)nrow * NGROUPS + ky * 4);
    asm volatile("s_waitcnt vmcnt(0)" ::: "memory");
    const float sc[4] = {sc4.x, sc4.y, sc4.z, sc4.w};

    // frag-read row + swizzle key
    const int rr = wv * 16 + ln;
    const int rx = rr & 7;

    f32x4 acc[4], pg[4];
    #pragma unroll
    for (int t = 0; t < 4; ++t) {
        acc[t] = (f32x4){0.f, 0.f, 0.f, 0.f};
        pg[t]  = (f32x4){0.f, 0.f, 0.f, 0.f};
    }

    // prologue: stages 0..3 in flight, interleaved W,X (6 ops per stage)
    WSTAGE(0, 0); XLOAD(0, 0);
    WSTAGE(1, 1); XLOAD(1, 1);
    WSTAGE(2, 2); XLOAD(2, 2);
    WSTAGE(3, 3); XLOAD(3, 3);

    #pragma unroll
    for (int s = 0; s < NST; ++s) {
        // issue next w stage (top of window)
        if (s + DIST < NST) WSTAGE(s + DIST, (s + DIST) % NBUF);

        // single counted wait: drains exactly stage s (w pair + x quad),
        // retains stages s+1..s+4. Never 0 until the tail.
        if (s + DIST < NST)      asm volatile("s_waitcnt vmcnt(20)" ::: "memory");
        else if (s == NST - 4)   asm volatile("s_waitcnt vmcnt(18)" ::: "memory");
        else if (s == NST - 3)   asm volatile("s_waitcnt vmcnt(12)" ::: "memory");
        else if (s == NST - 2)   asm volatile("s_waitcnt vmcnt(6)"  ::: "memory");
        else                     asm volatile("s_waitcnt vmcnt(0)"  ::: "memory");
        __builtin_amdgcn_sched_barrier(0);

        // w frag: two swizzled 16B chunks of (wave-private) row rr
        const int buf = s % NBUF;
        const int cA  = (quad * 2) ^ rx;
        const int cB  = (quad * 2 + 1) ^ rx;
        f32x4 fa = *(const f32x4*)&lds_w[buf][rr * 32 + cA * 4];
        f32x4 fb = *(const f32x4*)&lds_w[buf][rr * 32 + cB * 4];
        bf16x8 wf = {(__bf16)fa.x, (__bf16)fa.y, (__bf16)fa.z, (__bf16)fa.w,
                     (__bf16)fb.x, (__bf16)fb.y, (__bf16)fb.z, (__bf16)fb.w};

        #pragma unroll
        for (int t = 0; t < 4; ++t)
            pg[t] = __builtin_amdgcn_mfma_f32_16x16x32_bf16(xr[s & 3][t], wf,
                                                            pg[t], 0, 0, 0);

        // refill the x ring slot just consumed (bottom of window)
        if (s + DIST < NST) XLOAD(s & 3, s + DIST);

        // per-128k scale group boundary: fold pg into acc
        if ((s & 3) == 3) {
            const float sg = sc[s >> 2];
            #pragma unroll
            for (int t = 0; t < 4; ++t) {
                #pragma unroll
                for (int r = 0; r < 4; ++r) {
                    acc[t][r] += sg * pg[t][r];
                    pg[t][r] = 0.f;
                }
            }
        }
    }

    // atomic split-K epilogue -> out[m][n]  (C/D: m = t*16+quad*4+r, col = ln)
    float* op = out + n0 + wv * 16 + ln;
    #pragma unroll
    for (int t = 0; t < 4; ++t)
        #pragma unroll
        for (int r = 0; r < 4; ++r)
            unsafeAtomicAdd(&op[(size_t)(t * 16 + quad * 4 + r) * Nd], acc[t][r]);
#undef WSTAGE
#undef XLOAD
}

extern "C" void kernel_launch(void* const* d_in, const int* in_sizes, int n_in,
                              void* d_out, int out_size, void* d_ws, size_t ws_size,
                              hipStream_t stream) {
    const float* x     = (const float*)d_in[0];  // [64][4096]
    const float* w     = (const float*)d_in[1];  // [11008][4096]
    const float* scale = (const float*)d_in[2];  // [11008][32]
    const float* bias  = (const float*)d_in[3];  // [11008]
    float* out = (float*)d_out;                  // [64][11008] f32
    float* ws  = (float*)d_ws;                   // xf bf16 (512 KB)

    __bf16* xf = (__bf16*)ws;                    // 16B-aligned

    prep<<<816, 256, 0, stream>>>(x, xf, bias, out);

    dim3 grid1(Nd / BN, KSPLIT);
    qlinear_pass1<<<grid1, 256, 0, stream>>>(w, xf, scale, out);
}